// Round 5
// baseline (201.294 us; speedup 1.0000x reference)
//
#include <hip/hip_runtime.h>
#include <stdint.h>

#define N_IMG 256
#define HW 196
#define CDIM 512
#define RSTRIDE 208

#define F_EPS_POS 0.65f
#define F_EPS_NEG 0.40f
#define F_INV_TAU (1.0f/0.03f)
#define F_TEMP 0.07f

typedef __attribute__((ext_vector_type(8))) short bf16x8;
typedef __attribute__((ext_vector_type(4))) unsigned short u16x4;
typedef __attribute__((ext_vector_type(4))) float f32x4;

__device__ __forceinline__ unsigned short f2bf(float x){
    unsigned int u = __float_as_uint(x);
    u = (u + 0x7FFFu + ((u >> 16) & 1u)) >> 16;
    return (unsigned short)u;
}
__device__ __forceinline__ float sigm(float x){ return 1.0f/(1.0f + __expf(-x)); }

// ---------------- kernel 1: audio L2-normalize -> bf16 ----------------
__global__ void audio_norm_k(const float* __restrict__ audio,
                             unsigned short* __restrict__ abf){
    int k = blockIdx.x, t = threadIdx.x;
    __shared__ float red[256];
    float v0 = audio[k*CDIM + t];
    float v1 = audio[k*CDIM + t + 256];
    red[t] = v0*v0 + v1*v1;
    __syncthreads();
    for (int s = 128; s > 0; s >>= 1){
        if (t < s) red[t] += red[t+s];
        __syncthreads();
    }
    float rrt = 1.0f / sqrtf(red[0]);
    abf[k*CDIM + t]       = f2bf(v0*rrt);
    abf[k*CDIM + t + 256] = f2bf(v1*rrt);
}

// ---------------- kernel 1b: frame -> bf16 (swizzled) + row rsqrt ----------------
// Streaming: one wave per spatial row. Lane layout and ss summation order are
// bit-identical to the previous in-main_k storeT (v[0]=row[lane], v[1]=row[lane+64],
// 8-term sum, xor-butterfly 1..32) -> rnorm values unchanged.
// bf16 row is written with its 16B chunks XOR-permuted by ((p&3)<<4) so that
// main_k's LINEAR global_load_lds + swizzled ds_read reconstruct the original
// layout (swizzle-source + swizzle-read, linear LDS dest: T21 discipline).
__global__ __launch_bounds__(512)
void fnorm_k(const float* __restrict__ frame,
             unsigned short* __restrict__ fbf,
             float* __restrict__ rnorm){
    const int lane = threadIdx.x & 63, wid = threadIdx.x >> 6;
    const int p = blockIdx.x * 8 + wid;         // grid.x = 25 -> p in 0..199
    const int n = blockIdx.y;
    if (p >= HW) return;
    const float4* src = (const float4*)(frame + ((size_t)n*HW + p)*CDIM);
    float4 a = src[lane], b = src[lane + 64];
    float ss = a.x*a.x + a.y*a.y + a.z*a.z + a.w*a.w
             + b.x*b.x + b.y*b.y + b.z*b.z + b.w*b.w;
    #pragma unroll
    for (int d = 1; d < 64; d <<= 1) ss += __shfl_xor(ss, d, 64);
    char* dst = (char*)(fbf + ((size_t)n*HW + p)*CDIM);
    u16x4 u0 = { f2bf(a.x), f2bf(a.y), f2bf(a.z), f2bf(a.w) };
    u16x4 u1 = { f2bf(b.x), f2bf(b.y), f2bf(b.z), f2bf(b.w) };
    const int sw = (p & 3) << 4;                // XOR key on byte bits 4-5
    *(u16x4*)(dst + (((lane*8) ^ sw)))         = u0;
    *(u16x4*)(dst + (512 + ((lane*8) ^ sw)))   = u1;
    if (lane == 0)
        rnorm[(size_t)n*RSTRIDE + p] = (ss > 0.f) ? (1.0f/sqrtf(ss)) : 0.f;
}

// ---------------- kernel 2: main GEMM + weighted reductions ----------------
// grid = 256 (1 block per n), block = 512 (8 waves). B-frags in regs as before.
// Staging is now 2 x global_load_lds_dwordx4 per wave per tile: no staging
// VGPRs, no conversion VALU, no shuffle chains, no ds_writes. LDS rows are
// linear 1024B (gload_lds requirement); ds_read applies the (row&3)<<4 XOR
// (pre-applied to the global source by fnorm_k) -> granule-uniform, conflict-
// free. Same MFMA j-order / accumulation / epilogue as round 4 -> bitwise-
// identical results.
__global__ __launch_bounds__(512, 2)
void main_k(const unsigned short* __restrict__ fbf,
            const float* __restrict__ rnorm,
            const unsigned short* __restrict__ abf,
            float* __restrict__ num, float* __restrict__ den,
            float* __restrict__ hnum, float* __restrict__ hden){
    __shared__ unsigned short fT[2][16*CDIM];   // 2 x 16KB, linear rows

    const int t    = threadIdx.x;
    const int n    = blockIdx.x;
    const int lane = t & 63, wid = t >> 6;      // wid 0..7
    const int col  = lane & 15, quad = lane >> 4;
    const int kg0  = wid*32 + col;              // this wave's k columns
    const int kg1  = kg0 + 16;

    // ---- B fragments in registers (2 x 16 x bf16x8 = 128 VGPRs) ----
    bf16x8 B0[16], B1[16];
    {
        const unsigned short* b0p = abf + (size_t)kg0*CDIM + quad*8;
        const unsigned short* b1p = abf + (size_t)kg1*CDIM + quad*8;
        #pragma unroll
        for (int j = 0; j < 16; ++j){
            B0[j] = *(const bf16x8*)(b0p + j*32);
            B1[j] = *(const bf16x8*)(b1p + j*32);
        }
    }

    const int r0 = 2*wid, r1 = r0 + 1;          // this wave's tile rows
    const char* gbase = (const char*)(fbf + (size_t)n*HW*CDIM);

    float en0=0.f, en1=0.f, ed0=0.f, ed1=0.f;
    float hn0=0.f, hn1=0.f, hd0=0.f, hd1=0.f;

    // async global->LDS staging: LDS dest uniform base + lane*16 (linear),
    // global src per-lane (already swizzled by fnorm_k).
    auto stage = [&](int pt, int buf){
        int p0 = pt*16 + r0; if (p0 > HW-1) p0 = HW-1;  // pad rows duplicate
        int p1 = pt*16 + r1; if (p1 > HW-1) p1 = HW-1;  // row 195; discarded
        const char* s0 = gbase + (size_t)p0*(CDIM*2) + lane*16;
        const char* s1 = gbase + (size_t)p1*(CDIM*2) + lane*16;
        __builtin_amdgcn_global_load_lds(
            (const __attribute__((address_space(1))) void*)s0,
            (__attribute__((address_space(3))) void*)&fT[buf][r0*CDIM], 16, 0, 0);
        __builtin_amdgcn_global_load_lds(
            (const __attribute__((address_space(1))) void*)s1,
            (__attribute__((address_space(3))) void*)&fT[buf][r1*CDIM], 16, 0, 0);
    };

    stage(0, 0);
    __syncthreads();

    // swizzled A-frag read base: byte = col*1024 + ((quad ^ (col&3))<<4) + j*64
    const unsigned short* fb0 = (const unsigned short*)
        ((const char*)fT[0] + col*1024 + ((quad ^ (col & 3)) << 4));
    const unsigned short* fb1 = (const unsigned short*)
        ((const char*)fT[1] + col*1024 + ((quad ^ (col & 3)) << 4));

    for (int pt = 0; pt < 13; ++pt){
        if (pt < 12) stage(pt + 1, (pt + 1) & 1);   // issue before compute

        const unsigned short* fb = (pt & 1) ? fb1 : fb0;
        f32x4 acc0 = {0.f,0.f,0.f,0.f};
        f32x4 acc1 = {0.f,0.f,0.f,0.f};
        #pragma unroll
        for (int j = 0; j < 16; ++j){
            bf16x8 a = *(const bf16x8*)(fb + j*32);
            acc0 = __builtin_amdgcn_mfma_f32_16x16x32_bf16(a, B0[j], acc0, 0, 0, 0);
            acc1 = __builtin_amdgcn_mfma_f32_16x16x32_bf16(a, B1[j], acc1, 0, 0, 0);
        }
        f32x4 rn4 = *(const f32x4*)(rnorm + (size_t)n*RSTRIDE + pt*16 + quad*4);
        #pragma unroll
        for (int rr = 0; rr < 4; ++rr){
            int prow = pt*16 + quad*4 + rr;
            if (prow < HW){
                float s0 = acc0[rr] * rn4[rr];
                float s1 = acc1[rr] * rn4[rr];
                float w0 = sigm((s0 - F_EPS_POS) * F_INV_TAU);
                float w1 = sigm((s1 - F_EPS_POS) * F_INV_TAU);
                en0 += w0*s0; ed0 += w0;
                en1 += w1*s1; ed1 += w1;
                if (kg0 == n){ float wn = 1.f - sigm((s0 - F_EPS_NEG) * F_INV_TAU); hn0 += wn*s0; hd0 += wn; }
                if (kg1 == n){ float wn = 1.f - sigm((s1 - F_EPS_NEG) * F_INV_TAU); hn1 += wn*s1; hd1 += wn; }
            }
        }
        __syncthreads();   // drains this tile's gload_lds; next buffer ready
    }

    // reduce across quads (rows live in quads; k identical per quad)
    en0 += __shfl_xor(en0, 16, 64); en0 += __shfl_xor(en0, 32, 64);
    ed0 += __shfl_xor(ed0, 16, 64); ed0 += __shfl_xor(ed0, 32, 64);
    en1 += __shfl_xor(en1, 16, 64); en1 += __shfl_xor(en1, 32, 64);
    ed1 += __shfl_xor(ed1, 16, 64); ed1 += __shfl_xor(ed1, 32, 64);
    hn0 += __shfl_xor(hn0, 16, 64); hn0 += __shfl_xor(hn0, 32, 64);
    hd0 += __shfl_xor(hd0, 16, 64); hd0 += __shfl_xor(hd0, 32, 64);
    hn1 += __shfl_xor(hn1, 16, 64); hn1 += __shfl_xor(hn1, 32, 64);
    hd1 += __shfl_xor(hd1, 16, 64); hd1 += __shfl_xor(hd1, 32, 64);

    if (quad == 0){
        num[n*N_IMG + kg0] = en0;  den[n*N_IMG + kg0] = ed0;
        num[n*N_IMG + kg1] = en1;  den[n*N_IMG + kg1] = ed1;
        if (kg0 == n){ hnum[n] = hn0; hden[n] = hd0; }
        if (kg1 == n){ hnum[n] = hn1; hden[n] = hd1; }
    }
}

// ---------------- kernel 3: per-n Pi_d / Ni_d (parallel over n) ----------------
__global__ void pd_k(const float* __restrict__ num, const float* __restrict__ den,
                     const float* __restrict__ hnum, const float* __restrict__ hden,
                     float* __restrict__ Pi_d, float* __restrict__ Ni_d){
    int nn = blockIdx.x, t = threadIdx.x;
    __shared__ float red[256];
    __shared__ float diagv;
    float ratio = num[nn*N_IMG + t] / den[nn*N_IMG + t];
    if (t == nn) diagv = ratio;
    red[t] = ratio * (t == nn ? -99.f : 1.f);
    __syncthreads();
    for (int s = 128; s > 0; s >>= 1){
        if (t < s) red[t] += red[t+s];
        __syncthreads();
    }
    if (t == 0){
        Pi_d[nn] = F_TEMP * diagv;
        Ni_d[nn] = F_TEMP * (hnum[nn]/hden[nn] + red[0]);
    }
}

// ---------------- kernel 4: broadcast (N,N) log-sum + atomic total ----------------
// loss = (1/N) * sum_{i,j} log(1 + exp(Ni_d[j] - Pi_d[i]))
__global__ void loss_k(const float* __restrict__ Pi_d, const float* __restrict__ Ni_d,
                       float* __restrict__ out){
    int i = blockIdx.x, j = threadIdx.x;
    __shared__ float red[256];
    float x = Ni_d[j] - Pi_d[i];
    red[j] = (x > 20.f) ? x : log1pf(__expf(x));
    __syncthreads();
    for (int s = 128; s > 0; s >>= 1){
        if (j < s) red[j] += red[j+s];
        __syncthreads();
    }
    if (j == 0) atomicAdd(out, red[0] * (1.0f/(float)N_IMG));
}

extern "C" void kernel_launch(void* const* d_in, const int* in_sizes, int n_in,
                              void* d_out, int out_size, void* d_ws, size_t ws_size,
                              hipStream_t stream) {
    const float* frame = (const float*)d_in[0];
    const float* audio = (const float*)d_in[1];
    float* out = (float*)d_out;
    char* ws = (char*)d_ws;

    unsigned short* abf   = (unsigned short*)(ws);                  // 262144 B
    unsigned short* fbf   = (unsigned short*)(ws + 262144);         // 51380224 B
    float*          rnorm = (float*)(ws + 51642368);                // 212992 B
    float*          num   = (float*)(ws + 51855360);                // 262144 B
    float*          den   = (float*)(ws + 52117504);                // 262144 B
    float*          hnum  = (float*)(ws + 52379648);                // 1024 B
    float*          hden  = (float*)(ws + 52380672);                // 1024 B
    float*          Pi_d  = (float*)(ws + 52381696);                // 1024 B
    float*          Ni_d  = (float*)(ws + 52382720);                // 1024 B

    hipMemsetAsync(out, 0, sizeof(float), stream);                  // capture-legal

    audio_norm_k<<<N_IMG, 256, 0, stream>>>(audio, abf);
    fnorm_k<<<dim3(25, N_IMG), 512, 0, stream>>>(frame, fbf, rnorm);
    main_k<<<N_IMG, 512, 0, stream>>>(fbf, rnorm, abf, num, den, hnum, hden);
    pd_k<<<N_IMG, 256, 0, stream>>>(num, den, hnum, hden, Pi_d, Ni_d);
    loss_k<<<N_IMG, 256, 0, stream>>>(Pi_d, Ni_d, out);
}

// Round 6
// 175.605 us; speedup vs baseline: 1.1463x; 1.1463x over previous
//
#include <hip/hip_runtime.h>
#include <stdint.h>

#define N_IMG 256
#define HW 196
#define CDIM 512

#define F_EPS_POS 0.65f
#define F_EPS_NEG 0.40f
#define F_INV_TAU (1.0f/0.03f)
#define F_TEMP 0.07f

typedef __attribute__((ext_vector_type(8))) short bf16x8;
typedef __attribute__((ext_vector_type(4))) unsigned short u16x4;
typedef __attribute__((ext_vector_type(4))) float f32x4;

__device__ __forceinline__ unsigned short f2bf(float x){
    unsigned int u = __float_as_uint(x);
    u = (u + 0x7FFFu + ((u >> 16) & 1u)) >> 16;
    return (unsigned short)u;
}
__device__ __forceinline__ float sigm(float x){ return 1.0f/(1.0f + __expf(-x)); }

// ---------------- kernel 1: audio L2-normalize -> bf16 ----------------
__global__ void audio_norm_k(const float* __restrict__ audio,
                             unsigned short* __restrict__ abf){
    int k = blockIdx.x, t = threadIdx.x;
    __shared__ float red[256];
    float v0 = audio[k*CDIM + t];
    float v1 = audio[k*CDIM + t + 256];
    red[t] = v0*v0 + v1*v1;
    __syncthreads();
    for (int s = 128; s > 0; s >>= 1){
        if (t < s) red[t] += red[t+s];
        __syncthreads();
    }
    float rrt = 1.0f / sqrtf(red[0]);
    abf[k*CDIM + t]       = f2bf(v0*rrt);
    abf[k*CDIM + t + 256] = f2bf(v1*rrt);
}

// ---------------- kernel 2: main GEMM + weighted reductions ----------------
// grid = 512 = (n, k-half): bid&255 = n, bid>>8 = kh (kh-twins of an n are 256
// dispatches apart -> same XCD slot -> staged frame rows L2-shared).
// block = 512 (8 waves, 4 waves/SIMD); each wave owns 16 k-cols -> B-frags are
// 16 x bf16x8 = 64 VGPRs. TOTAL demand ~115 regs <= the 128-reg cap from
// __launch_bounds__(512,4): the B-fragments actually STAY in registers.
// (Rounds 0-5 all demanded 150-200 regs under a 64-128 cap -> B spilled to
// scratch / re-fetched every tile; VGPR_Count<=128 in every rocprof row was
// the smoking gun. That hidden reload traffic was the ~60us invariant.)
// 2 blocks/CU co-resident: one block's barrier drain hides under the other's
// compute. Staging layout, conversion, rsqrt butterfly, and per-(n,k) hw
// accumulation order are IDENTICAL to round 2 -> bitwise-identical outputs.
__global__ __launch_bounds__(512, 4)
void main_k(const float* __restrict__ frame,
            const unsigned short* __restrict__ abf,
            float* __restrict__ num, float* __restrict__ den,
            float* __restrict__ hnum, float* __restrict__ hden){
    __shared__ unsigned short fT[2][16*520];   // 520 stride: conflict-free b128
    __shared__ float rnormS[2][16];

    const int t    = threadIdx.x;
    const int n    = blockIdx.x & 255;
    const int kh   = blockIdx.x >> 8;          // k-half: 0 or 1
    const int lane = t & 63, wid = t >> 6;     // wid 0..7
    const int col  = lane & 15, quad = lane >> 4;
    const int kg   = kh*128 + wid*16 + col;    // this wave's k column

    // ---- B fragments in registers (16 x bf16x8 = 64 VGPRs) ----
    bf16x8 B[16];
    {
        const unsigned short* bp = abf + (size_t)kg*CDIM + quad*8;
        #pragma unroll
        for (int j = 0; j < 16; ++j) B[j] = *(const bf16x8*)(bp + j*32);
    }

    const int r0 = 2*wid, r1 = r0 + 1;         // this wave's tile rows

    float en = 0.f, ed = 0.f, hn = 0.f, hd = 0.f;

    const float4* fbase_g = (const float4*)(frame + (size_t)n*HW*CDIM);

    // perfectly coalesced stage loads: each instr = 64 lanes x 16B contiguous
    auto loadT = [&](int pt, float4* v){
        int p0 = pt*16 + r0; if (p0 > HW-1) p0 = HW-1;   // clamped pad rows dup
        int p1 = pt*16 + r1; if (p1 > HW-1) p1 = HW-1;   // row 195; discarded
        const float4* s0 = fbase_g + (size_t)p0*(CDIM/4);
        const float4* s1 = fbase_g + (size_t)p1*(CDIM/4);
        v[0] = s0[lane]; v[1] = s0[lane + 64];
        v[2] = s1[lane]; v[3] = s1[lane + 64];
    };
    // convert+write rows into buf, full-wave row rsqrt via butterfly shuffle
    auto storeT = [&](const float4* v, int buf){
        float ss0 = v[0].x*v[0].x + v[0].y*v[0].y + v[0].z*v[0].z + v[0].w*v[0].w
                  + v[1].x*v[1].x + v[1].y*v[1].y + v[1].z*v[1].z + v[1].w*v[1].w;
        float ss1 = v[2].x*v[2].x + v[2].y*v[2].y + v[2].z*v[2].z + v[2].w*v[2].w
                  + v[3].x*v[3].x + v[3].y*v[3].y + v[3].z*v[3].z + v[3].w*v[3].w;
        unsigned short* d0 = fT[buf] + r0*520;
        unsigned short* d1 = fT[buf] + r1*520;
        u16x4 u0 = { f2bf(v[0].x), f2bf(v[0].y), f2bf(v[0].z), f2bf(v[0].w) };
        u16x4 u1 = { f2bf(v[1].x), f2bf(v[1].y), f2bf(v[1].z), f2bf(v[1].w) };
        u16x4 u2 = { f2bf(v[2].x), f2bf(v[2].y), f2bf(v[2].z), f2bf(v[2].w) };
        u16x4 u3 = { f2bf(v[3].x), f2bf(v[3].y), f2bf(v[3].z), f2bf(v[3].w) };
        *(u16x4*)(d0 + lane*4)       = u0;
        *(u16x4*)(d0 + 256 + lane*4) = u1;
        *(u16x4*)(d1 + lane*4)       = u2;
        *(u16x4*)(d1 + 256 + lane*4) = u3;
        #pragma unroll
        for (int dd = 1; dd < 64; dd <<= 1){
            ss0 += __shfl_xor(ss0, dd, 64);
            ss1 += __shfl_xor(ss1, dd, 64);
        }
        if (lane == 0){
            rnormS[buf][r0] = (ss0 > 0.f) ? (1.0f/sqrtf(ss0)) : 0.f;
            rnormS[buf][r1] = (ss1 > 0.f) ? (1.0f/sqrtf(ss1)) : 0.f;
        }
    };

    // prologue: tile 0 into buffer 0
    {
        float4 v[4];
        loadT(0, v);
        storeT(v, 0);
    }
    __syncthreads();

    for (int pt = 0; pt < 13; ++pt){
        const int cur = pt & 1, nxt = cur ^ 1;
        const bool hasNext = (pt < 12);

        float4 v[4];
        if (hasNext) loadT(pt + 1, v);   // prefetch: in flight under MFMA phase

        // ---- MFMA phase on buf[cur]: 16 j-steps, single acc chain ----
        const unsigned short* fbase = fT[cur] + col*520 + quad*8;
        f32x4 acc = {0.f,0.f,0.f,0.f};
        #pragma unroll
        for (int j = 0; j < 16; ++j){
            bf16x8 a = *(const bf16x8*)(fbase + j*32);
            acc = __builtin_amdgcn_mfma_f32_16x16x32_bf16(a, B[j], acc, 0, 0, 0);
        }
        f32x4 rn4 = *(const f32x4*)(&rnormS[cur][quad*4]);
        #pragma unroll
        for (int rr = 0; rr < 4; ++rr){
            int prow = pt*16 + quad*4 + rr;
            if (prow < HW){
                float s  = acc[rr] * rn4[rr];
                float wp = sigm((s - F_EPS_POS) * F_INV_TAU);
                en += wp*s; ed += wp;
                if (kg == n){ float wn = 1.f - sigm((s - F_EPS_NEG) * F_INV_TAU); hn += wn*s; hd += wn; }
            }
        }

        if (hasNext) storeT(v, nxt);
        __syncthreads();
    }

    // reduce across quads (rows live in quads; kg identical per quad)
    en += __shfl_xor(en, 16, 64); en += __shfl_xor(en, 32, 64);
    ed += __shfl_xor(ed, 16, 64); ed += __shfl_xor(ed, 32, 64);
    hn += __shfl_xor(hn, 16, 64); hn += __shfl_xor(hn, 32, 64);
    hd += __shfl_xor(hd, 16, 64); hd += __shfl_xor(hd, 32, 64);

    if (quad == 0){
        num[n*N_IMG + kg] = en;  den[n*N_IMG + kg] = ed;
        if (kg == n){ hnum[n] = hn; hden[n] = hd; }
    }
}

// ---------------- kernel 3: per-n Pi_d / Ni_d (parallel over n) ----------------
__global__ void pd_k(const float* __restrict__ num, const float* __restrict__ den,
                     const float* __restrict__ hnum, const float* __restrict__ hden,
                     float* __restrict__ Pi_d, float* __restrict__ Ni_d){
    int nn = blockIdx.x, t = threadIdx.x;
    __shared__ float red[256];
    __shared__ float diagv;
    float ratio = num[nn*N_IMG + t] / den[nn*N_IMG + t];
    if (t == nn) diagv = ratio;
    red[t] = ratio * (t == nn ? -99.f : 1.f);
    __syncthreads();
    for (int s = 128; s > 0; s >>= 1){
        if (t < s) red[t] += red[t+s];
        __syncthreads();
    }
    if (t == 0){
        Pi_d[nn] = F_TEMP * diagv;
        Ni_d[nn] = F_TEMP * (hnum[nn]/hden[nn] + red[0]);
    }
}

// ---------------- kernel 4: broadcast (N,N) log-sum + atomic total ----------------
// loss = (1/N) * sum_{i,j} log(1 + exp(Ni_d[j] - Pi_d[i]))
__global__ void loss_k(const float* __restrict__ Pi_d, const float* __restrict__ Ni_d,
                       float* __restrict__ out){
    int i = blockIdx.x, j = threadIdx.x;
    __shared__ float red[256];
    float x = Ni_d[j] - Pi_d[i];
    red[j] = (x > 20.f) ? x : log1pf(__expf(x));
    __syncthreads();
    for (int s = 128; s > 0; s >>= 1){
        if (j < s) red[j] += red[j+s];
        __syncthreads();
    }
    if (j == 0) atomicAdd(out, red[0] * (1.0f/(float)N_IMG));
}

extern "C" void kernel_launch(void* const* d_in, const int* in_sizes, int n_in,
                              void* d_out, int out_size, void* d_ws, size_t ws_size,
                              hipStream_t stream) {
    const float* frame = (const float*)d_in[0];
    const float* audio = (const float*)d_in[1];
    float* out = (float*)d_out;
    char* ws = (char*)d_ws;

    unsigned short* abf = (unsigned short*)(ws);            // 262144 B
    float* num  = (float*)(ws + 262144);                    // 262144 B
    float* den  = (float*)(ws + 524288);                    // 262144 B
    float* hnum = (float*)(ws + 786432);                    // 1024 B
    float* hden = (float*)(ws + 787456);                    // 1024 B
    float* Pi_d = (float*)(ws + 788480);                    // 1024 B
    float* Ni_d = (float*)(ws + 789504);                    // 1024 B

    hipMemsetAsync(out, 0, sizeof(float), stream);          // capture-legal

    audio_norm_k<<<N_IMG, 256, 0, stream>>>(audio, abf);
    main_k<<<N_IMG*2, 512, 0, stream>>>(frame, abf, num, den, hnum, hden);
    pd_k<<<N_IMG, 256, 0, stream>>>(num, den, hnum, hden, Pi_d, Ni_d);
    loss_k<<<N_IMG, 256, 0, stream>>>(Pi_d, Ni_d, out);
}

// Round 7
// 174.129 us; speedup vs baseline: 1.1560x; 1.0085x over previous
//
#include <hip/hip_runtime.h>
#include <stdint.h>

#define N_IMG 256
#define HW 196
#define CDIM 512

#define F_EPS_POS 0.65f
#define F_EPS_NEG 0.40f
#define F_INV_TAU (1.0f/0.03f)
#define F_TEMP 0.07f

typedef __attribute__((ext_vector_type(8))) short bf16x8;
typedef __attribute__((ext_vector_type(4))) unsigned short u16x4;
typedef __attribute__((ext_vector_type(4))) float f32x4;

__device__ __forceinline__ unsigned short f2bf(float x){
    unsigned int u = __float_as_uint(x);
    u = (u + 0x7FFFu + ((u >> 16) & 1u)) >> 16;
    return (unsigned short)u;
}
__device__ __forceinline__ float sigm(float x){ return 1.0f/(1.0f + __expf(-x)); }

// ---------------- kernel 1: audio L2-normalize -> bf16 ----------------
__global__ void audio_norm_k(const float* __restrict__ audio,
                             unsigned short* __restrict__ abf){
    int k = blockIdx.x, t = threadIdx.x;
    __shared__ float red[256];
    float v0 = audio[k*CDIM + t];
    float v1 = audio[k*CDIM + t + 256];
    red[t] = v0*v0 + v1*v1;
    __syncthreads();
    for (int s = 128; s > 0; s >>= 1){
        if (t < s) red[t] += red[t+s];
        __syncthreads();
    }
    float rrt = 1.0f / sqrtf(red[0]);
    abf[k*CDIM + t]       = f2bf(v0*rrt);
    abf[k*CDIM + t + 256] = f2bf(v1*rrt);
}

// ---------------- kernel 2: main GEMM + weighted reductions ----------------
// ROUND-7 CHANGE (A/B vs round 2, everything else bitwise-identical):
//  (1) amdgpu_waves_per_eu(2,2): max=2 waves/EU removes the allocator's
//      incentive to shrink to the 128-reg occupancy tier. Rounds 0-6 all
//      show VGPR_Count <= 128 while B-fragment demand alone is 128 -> the
//      compiler REMATERIALIZED the B loads from L2 inside the MFMA j-loop
//      every tile (free-spill, invisible in WRITE_SIZE). 32 L2 loads x 13
//      tiles on the MFMA critical path is the ~58us invariant no staging
//      change could touch.
//  (2) empty-asm "+v" anchors on all 32 B-fragments: asm outputs are not
//      rematerializable -> B must stay VGPR-resident across the whole loop.
// Expected tell: VGPR_Count ~180-230, main_k ~18-28us.
__global__ __launch_bounds__(512) __attribute__((amdgpu_waves_per_eu(2, 2)))
void main_k(const float* __restrict__ frame,
            const unsigned short* __restrict__ abf,
            float* __restrict__ num, float* __restrict__ den,
            float* __restrict__ hnum, float* __restrict__ hden){
    __shared__ unsigned short fT[2][16*520];   // 520 stride: conflict-free b128
    __shared__ float rnormS[2][16];

    const int t    = threadIdx.x;
    const int n    = blockIdx.x;
    const int lane = t & 63, wid = t >> 6;     // wid 0..7
    const int col  = lane & 15, quad = lane >> 4;
    const int kg0  = wid*32 + col;             // this wave's k columns
    const int kg1  = kg0 + 16;

    // ---- B fragments in registers (2 x 16 x bf16x8 = 128 VGPRs) ----
    bf16x8 B0[16], B1[16];
    {
        const unsigned short* b0p = abf + (size_t)kg0*CDIM + quad*8;
        const unsigned short* b1p = abf + (size_t)kg1*CDIM + quad*8;
        #pragma unroll
        for (int j = 0; j < 16; ++j){
            B0[j] = *(const bf16x8*)(b0p + j*32);
            B1[j] = *(const bf16x8*)(b1p + j*32);
        }
    }
    // liveness anchors: forbid rematerialization of the B loads
#define ANCH8(a,b,c,d,e,f,g,h) \
    asm volatile("" : "+v"(a),"+v"(b),"+v"(c),"+v"(d),"+v"(e),"+v"(f),"+v"(g),"+v"(h))
    ANCH8(B0[0],B0[1],B0[2],B0[3],B0[4],B0[5],B0[6],B0[7]);
    ANCH8(B0[8],B0[9],B0[10],B0[11],B0[12],B0[13],B0[14],B0[15]);
    ANCH8(B1[0],B1[1],B1[2],B1[3],B1[4],B1[5],B1[6],B1[7]);
    ANCH8(B1[8],B1[9],B1[10],B1[11],B1[12],B1[13],B1[14],B1[15]);
#undef ANCH8

    const int r0 = 2*wid, r1 = r0 + 1;         // this wave's tile rows

    float en0=0.f, en1=0.f, ed0=0.f, ed1=0.f;
    float hn0=0.f, hn1=0.f, hd0=0.f, hd1=0.f;

    const float4* fbase_g = (const float4*)(frame + (size_t)n*HW*CDIM);

    // perfectly coalesced stage loads: each instr = 64 lanes x 16B contiguous
    auto loadT = [&](int pt, float4* v){
        int p0 = pt*16 + r0; if (p0 > HW-1) p0 = HW-1;   // clamped pad rows dup
        int p1 = pt*16 + r1; if (p1 > HW-1) p1 = HW-1;   // row 195; discarded
        const float4* s0 = fbase_g + (size_t)p0*(CDIM/4);
        const float4* s1 = fbase_g + (size_t)p1*(CDIM/4);
        v[0] = s0[lane]; v[1] = s0[lane + 64];
        v[2] = s1[lane]; v[3] = s1[lane + 64];
    };
    // convert+write rows into buf, full-wave row rsqrt via butterfly shuffle
    auto storeT = [&](const float4* v, int buf){
        float ss0 = v[0].x*v[0].x + v[0].y*v[0].y + v[0].z*v[0].z + v[0].w*v[0].w
                  + v[1].x*v[1].x + v[1].y*v[1].y + v[1].z*v[1].z + v[1].w*v[1].w;
        float ss1 = v[2].x*v[2].x + v[2].y*v[2].y + v[2].z*v[2].z + v[2].w*v[2].w
                  + v[3].x*v[3].x + v[3].y*v[3].y + v[3].z*v[3].z + v[3].w*v[3].w;
        unsigned short* d0 = fT[buf] + r0*520;
        unsigned short* d1 = fT[buf] + r1*520;
        u16x4 u0 = { f2bf(v[0].x), f2bf(v[0].y), f2bf(v[0].z), f2bf(v[0].w) };
        u16x4 u1 = { f2bf(v[1].x), f2bf(v[1].y), f2bf(v[1].z), f2bf(v[1].w) };
        u16x4 u2 = { f2bf(v[2].x), f2bf(v[2].y), f2bf(v[2].z), f2bf(v[2].w) };
        u16x4 u3 = { f2bf(v[3].x), f2bf(v[3].y), f2bf(v[3].z), f2bf(v[3].w) };
        *(u16x4*)(d0 + lane*4)       = u0;
        *(u16x4*)(d0 + 256 + lane*4) = u1;
        *(u16x4*)(d1 + lane*4)       = u2;
        *(u16x4*)(d1 + 256 + lane*4) = u3;
        #pragma unroll
        for (int dd = 1; dd < 64; dd <<= 1){
            ss0 += __shfl_xor(ss0, dd, 64);
            ss1 += __shfl_xor(ss1, dd, 64);
        }
        if (lane == 0){
            rnormS[buf][r0] = (ss0 > 0.f) ? (1.0f/sqrtf(ss0)) : 0.f;
            rnormS[buf][r1] = (ss1 > 0.f) ? (1.0f/sqrtf(ss1)) : 0.f;
        }
    };

    // prologue: tile 0 into buffer 0
    {
        float4 v[4];
        loadT(0, v);
        storeT(v, 0);
    }
    __syncthreads();

    for (int pt = 0; pt < 13; ++pt){
        const int cur = pt & 1, nxt = cur ^ 1;
        const bool hasNext = (pt < 12);

        float4 v[4];
        if (hasNext) loadT(pt + 1, v);   // prefetch: in flight under MFMA phase

        // ---- MFMA phase on buf[cur]: 16 ds_read shared by 2 MFMA chains ----
        const unsigned short* fbase = fT[cur] + col*520 + quad*8;
        f32x4 acc0 = {0.f,0.f,0.f,0.f};
        f32x4 acc1 = {0.f,0.f,0.f,0.f};
        #pragma unroll
        for (int j = 0; j < 16; ++j){
            bf16x8 a = *(const bf16x8*)(fbase + j*32);
            acc0 = __builtin_amdgcn_mfma_f32_16x16x32_bf16(a, B0[j], acc0, 0, 0, 0);
            acc1 = __builtin_amdgcn_mfma_f32_16x16x32_bf16(a, B1[j], acc1, 0, 0, 0);
        }
        f32x4 rn4 = *(const f32x4*)(&rnormS[cur][quad*4]);
        #pragma unroll
        for (int rr = 0; rr < 4; ++rr){
            int prow = pt*16 + quad*4 + rr;
            if (prow < HW){
                float s0 = acc0[rr] * rn4[rr];
                float s1 = acc1[rr] * rn4[rr];
                float w0 = sigm((s0 - F_EPS_POS) * F_INV_TAU);
                float w1 = sigm((s1 - F_EPS_POS) * F_INV_TAU);
                en0 += w0*s0; ed0 += w0;
                en1 += w1*s1; ed1 += w1;
                if (kg0 == n){ float wn = 1.f - sigm((s0 - F_EPS_NEG) * F_INV_TAU); hn0 += wn*s0; hd0 += wn; }
                if (kg1 == n){ float wn = 1.f - sigm((s1 - F_EPS_NEG) * F_INV_TAU); hn1 += wn*s1; hd1 += wn; }
            }
        }

        if (hasNext) storeT(v, nxt);
        __syncthreads();
    }

    // reduce across quads (rows live in quads; k identical per quad)
    en0 += __shfl_xor(en0, 16, 64); en0 += __shfl_xor(en0, 32, 64);
    ed0 += __shfl_xor(ed0, 16, 64); ed0 += __shfl_xor(ed0, 32, 64);
    en1 += __shfl_xor(en1, 16, 64); en1 += __shfl_xor(en1, 32, 64);
    ed1 += __shfl_xor(ed1, 16, 64); ed1 += __shfl_xor(ed1, 32, 64);
    hn0 += __shfl_xor(hn0, 16, 64); hn0 += __shfl_xor(hn0, 32, 64);
    hd0 += __shfl_xor(hd0, 16, 64); hd0 += __shfl_xor(hd0, 32, 64);
    hn1 += __shfl_xor(hn1, 16, 64); hn1 += __shfl_xor(hn1, 32, 64);
    hd1 += __shfl_xor(hd1, 16, 64); hd1 += __shfl_xor(hd1, 32, 64);

    if (quad == 0){
        num[n*N_IMG + kg0] = en0;  den[n*N_IMG + kg0] = ed0;
        num[n*N_IMG + kg1] = en1;  den[n*N_IMG + kg1] = ed1;
        if (kg0 == n){ hnum[n] = hn0; hden[n] = hd0; }
        if (kg1 == n){ hnum[n] = hn1; hden[n] = hd1; }
    }
}

// ---------------- kernel 3: per-n Pi_d / Ni_d (parallel over n) ----------------
__global__ void pd_k(const float* __restrict__ num, const float* __restrict__ den,
                     const float* __restrict__ hnum, const float* __restrict__ hden,
                     float* __restrict__ Pi_d, float* __restrict__ Ni_d){
    int nn = blockIdx.x, t = threadIdx.x;
    __shared__ float red[256];
    __shared__ float diagv;
    float ratio = num[nn*N_IMG + t] / den[nn*N_IMG + t];
    if (t == nn) diagv = ratio;
    red[t] = ratio * (t == nn ? -99.f : 1.f);
    __syncthreads();
    for (int s = 128; s > 0; s >>= 1){
        if (t < s) red[t] += red[t+s];
        __syncthreads();
    }
    if (t == 0){
        Pi_d[nn] = F_TEMP * diagv;
        Ni_d[nn] = F_TEMP * (hnum[nn]/hden[nn] + red[0]);
    }
}

// ---------------- kernel 4: broadcast (N,N) log-sum + atomic total ----------------
// loss = (1/N) * sum_{i,j} log(1 + exp(Ni_d[j] - Pi_d[i]))
__global__ void loss_k(const float* __restrict__ Pi_d, const float* __restrict__ Ni_d,
                       float* __restrict__ out){
    int i = blockIdx.x, j = threadIdx.x;
    __shared__ float red[256];
    float x = Ni_d[j] - Pi_d[i];
    red[j] = (x > 20.f) ? x : log1pf(__expf(x));
    __syncthreads();
    for (int s = 128; s > 0; s >>= 1){
        if (j < s) red[j] += red[j+s];
        __syncthreads();
    }
    if (j == 0) atomicAdd(out, red[0] * (1.0f/(float)N_IMG));
}

extern "C" void kernel_launch(void* const* d_in, const int* in_sizes, int n_in,
                              void* d_out, int out_size, void* d_ws, size_t ws_size,
                              hipStream_t stream) {
    const float* frame = (const float*)d_in[0];
    const float* audio = (const float*)d_in[1];
    float* out = (float*)d_out;
    char* ws = (char*)d_ws;

    unsigned short* abf = (unsigned short*)(ws);            // 262144 B
    float* num  = (float*)(ws + 262144);                    // 262144 B
    float* den  = (float*)(ws + 524288);                    // 262144 B
    float* hnum = (float*)(ws + 786432);                    // 1024 B
    float* hden = (float*)(ws + 787456);                    // 1024 B
    float* Pi_d = (float*)(ws + 788480);                    // 1024 B
    float* Ni_d = (float*)(ws + 789504);                    // 1024 B

    hipMemsetAsync(out, 0, sizeof(float), stream);          // capture-legal

    audio_norm_k<<<N_IMG, 256, 0, stream>>>(audio, abf);
    main_k<<<N_IMG, 512, 0, stream>>>(frame, abf, num, den, hnum, hden);
    pd_k<<<N_IMG, 256, 0, stream>>>(num, den, hnum, hden, Pi_d, Ni_d);
    loss_k<<<N_IMG, 256, 0, stream>>>(Pi_d, Ni_d, out);
}